// Round 7
// baseline (6219.337 us; speedup 1.0000x reference)
//
#include <hip/hip_runtime.h>
#include <stdint.h>

#define B_   64
#define N_   256
#define S_   2000
#define K_   100
#define BIL_ 4
#define NITER_ 200
#define JITTER_ 1e-4f
#define SAFETY_ 0.5f
#define PART_ 4
#define SCH_  (S_ / PART_)   // 500 scenarios per block
#define GS_   50             // scenarios per g_kernel block

// ---- ws layout (offsets in float units; GT slot retained but unused) ----
#define OFF_LC16  ((size_t)0)                                   // (unused)
#define OFF_LR16  (OFF_LC16 + (size_t)B_ * N_ * N_ / 2)         // bf16 L row-major
#define OFF_GT    (OFF_LR16 + (size_t)B_ * N_ * N_ / 2)         // (unused, r14: GT deleted)
#define OFF_GR    (OFF_GT + (size_t)B_ * N_ * S_ / 2)           // bf16 G [b][s][m] (& temp fp32 Lc)
#define OFF_LOSS  (OFF_GR + (size_t)B_ * S_ * N_ / 2)           // uint loss keys, double-buffered
#define OFF_BAR   (OFF_LOSS + (size_t)2 * B_ * S_)              // int barrier counters

// ---------------- helpers ----------------
__device__ __forceinline__ float wred_f(float x) {
#pragma unroll
  for (int off = 32; off > 0; off >>= 1) x += __shfl_xor(x, off);
  return x;
}
__device__ __forceinline__ int wred_i(int x) {
#pragma unroll
  for (int off = 32; off > 0; off >>= 1) x += __shfl_xor(x, off);
  return x;
}
// monotone key: larger loss -> SMALLER key (top-K largest = K smallest keys)
__device__ __forceinline__ unsigned keyd(float x) {
  unsigned u = __float_as_uint(x);
  unsigned ku = (u & 0x80000000u) ? ~u : (u | 0x80000000u);
  return ~ku;
}
__device__ __forceinline__ uint16_t f2b(float f) {  // RNE fp32->bf16
  uint32_t u = __float_as_uint(f);
  uint32_t r = u + 0x7FFFu + ((u >> 16) & 1u);
  return (uint16_t)(r >> 16);
}
__device__ __forceinline__ float blo(uint32_t u) { return __uint_as_float(u << 16); }
__device__ __forceinline__ float bhi(uint32_t u) { return __uint_as_float(u & 0xFFFF0000u); }

// Michelot exact simplex projection (fixed point == reference sort formula); one wave.
__device__ __forceinline__ float michelot4(const float vp[4], float z) {
  bool act[4] = {true, true, true, true};
  float theta = 0.0f;
  int prev = -1;
  for (int pass = 0; pass < 300; ++pass) {
    float ls = 0.0f; int lc = 0;
#pragma unroll
    for (int j = 0; j < 4; ++j) { if (act[j]) { ls += vp[j]; lc += 1; } }
    ls = wred_f(ls);
    lc = wred_i(lc);
    theta = (ls - z) / (float)lc;
    if (lc == prev) break;
    prev = lc;
#pragma unroll
    for (int j = 0; j < 4; ++j) act[j] = (vp[j] > theta);
  }
  return theta;
}

__device__ __forceinline__ void proj_store(const float y[4], float fl_bil, float mass, float muf,
                                           const float* __restrict__ muB, int ln,
                                           float* w_s, float* c_sh) {
  float vp[4];
#pragma unroll
  for (int j = 0; j < 4; ++j) {
    const int n = 4 * ln + j;
    vp[j] = y[j] - ((n == BIL_) ? fl_bil : 0.0f);
  }
  const float theta = michelot4(vp, mass);
  const float4 m4 = *(const float4*)(muB + 4 * ln);
  const float mm[4] = {m4.x, m4.y, m4.z, m4.w};
  float wj[4];
  float cp = 0.0f;
#pragma unroll
  for (int j = 0; j < 4; ++j) {
    const int n = 4 * ln + j;
    wj[j] = fmaxf(vp[j] - theta, 0.0f) + ((n == BIL_) ? fl_bil : 0.0f);
    cp = fmaf(muf * mm[j], wj[j], cp);
  }
  cp = wred_f(cp);
  if (ln == 0) *c_sh = cp;
  *(float4*)(w_s + 4 * ln) = make_float4(wj[0], wj[1], wj[2], wj[3]);
}

// ---------------- Cholesky v3: one block (512 thr) per batch (proven r3) ----------------
__global__ __launch_bounds__(512) void chol_kernel(const float* __restrict__ sigma,
                                                   float* __restrict__ Lc) {
  const int b = blockIdx.x;
  const int tid = threadIdx.x;
  const int i = tid & 255;
  const int half = tid >> 8;
  const float* Sg = sigma + (size_t)b * N_ * N_;
  float* L = Lc + (size_t)b * N_ * N_;
  __shared__ __align__(16) float slab[248 * 8];
  __shared__ __align__(16) float spart[256][8];
  __shared__ __align__(16) float pnl[64];

  for (int j0 = 0; j0 < N_; j0 += 8) {
    for (int x = tid; x < j0 * 8; x += 512) {
      const int k = x >> 3, jj = x & 7;
      slab[x] = L[(size_t)k * N_ + (j0 + jj)];
    }
    float s[8];
    if (half == 0) {
#pragma unroll
      for (int jj = 0; jj < 8; ++jj) {
        float a = Sg[(size_t)(j0 + jj) * N_ + i];
        if (i == j0 + jj) a += JITTER_;
        s[jj] = a;
      }
    } else {
#pragma unroll
      for (int jj = 0; jj < 8; ++jj) s[jj] = 0.0f;
    }
    __syncthreads();

    const int kb = half ? (j0 >> 1) : 0;
    const int ke = half ? j0 : (j0 >> 1);
#pragma unroll 4
    for (int k = kb; k < ke; ++k) {
      const float lk = L[(size_t)k * N_ + i];
      const float4 h0 = *(const float4*)&slab[k * 8];
      const float4 h1 = *(const float4*)&slab[k * 8 + 4];
      s[0] = fmaf(-lk, h0.x, s[0]);
      s[1] = fmaf(-lk, h0.y, s[1]);
      s[2] = fmaf(-lk, h0.z, s[2]);
      s[3] = fmaf(-lk, h0.w, s[3]);
      s[4] = fmaf(-lk, h1.x, s[4]);
      s[5] = fmaf(-lk, h1.y, s[5]);
      s[6] = fmaf(-lk, h1.z, s[6]);
      s[7] = fmaf(-lk, h1.w, s[7]);
    }
    if (half == 1) {
      *(float4*)&spart[i][0] = make_float4(s[0], s[1], s[2], s[3]);
      *(float4*)&spart[i][4] = make_float4(s[4], s[5], s[6], s[7]);
    }
    __syncthreads();

    if (half == 0) {
      const float4 p0 = *(const float4*)&spart[i][0];
      const float4 p1 = *(const float4*)&spart[i][4];
      s[0] += p0.x; s[1] += p0.y; s[2] += p0.z; s[3] += p0.w;
      s[4] += p1.x; s[5] += p1.y; s[6] += p1.z; s[7] += p1.w;
      if ((i >> 3) == (j0 >> 3)) {
        const int base = j0 & 63;
        const int r = i & 7;
        float l[8], di[8];
#pragma unroll
        for (int m = 0; m < 8; ++m) {
          const float smv = __shfl(s[m], base + m);
          const float d = sqrtf(smv);
          const float dinv = 1.0f / d;
          di[m] = dinv;
          float lm;
          if (r == m) lm = d;
          else if (r > m) lm = s[m] * dinv;
          else lm = 0.0f;
          l[m] = lm;
#pragma unroll
          for (int mm = m + 1; mm < 8; ++mm) {
            s[mm] = fmaf(-lm, __shfl(lm, base + mm), s[mm]);
          }
        }
#pragma unroll
        for (int m = 0; m < 8; ++m) pnl[r * 8 + m] = (m < r) ? l[m] : ((m == r) ? di[r] : 0.0f);
#pragma unroll
        for (int m = 0; m < 8; ++m) L[(size_t)(j0 + m) * N_ + i] = l[m];
      }
    }
    __syncthreads();

    if (half == 0 && (i >> 3) != (j0 >> 3)) {
      float l[8];
      if (i > j0) {
#pragma unroll
        for (int m = 0; m < 8; ++m) {
          float sm = s[m];
#pragma unroll
          for (int mm = 0; mm < 8; ++mm) {
            if (mm < m) sm = fmaf(-l[mm], pnl[m * 8 + mm], sm);
          }
          l[m] = sm * pnl[m * 8 + m];
        }
      } else {
#pragma unroll
        for (int m = 0; m < 8; ++m) l[m] = 0.0f;
      }
#pragma unroll
      for (int m = 0; m < 8; ++m) L[(size_t)(j0 + m) * N_ + i] = l[m];
    }
    __syncthreads();
  }
}

// ---------------- pack L (row-major bf16: Lr16[i*N+k] = L[i][k]) ----------------
__global__ __launch_bounds__(256) void lpack_kernel(const float* __restrict__ Lc,
                                                    uint16_t* __restrict__ Lr16) {
  const int b = blockIdx.x;
  const float* Lp = Lc + (size_t)b * N_ * N_;
  uint16_t* R16 = Lr16 + (size_t)b * N_ * N_;
  __shared__ float tl[32][33];
  const int tx = threadIdx.x & 31;
  const int ty = threadIdx.x >> 5;
  for (int kt = 0; kt < 8; ++kt) {
    for (int it = 0; it < 8; ++it) {
#pragma unroll
      for (int rr = 0; rr < 4; ++rr) {
        const int k = kt * 32 + ty + 8 * rr;
        const int ii = it * 32 + tx;
        tl[ty + 8 * rr][tx] = Lp[(size_t)k * N_ + ii];
      }
      __syncthreads();
#pragma unroll
      for (int rr = 0; rr < 4; ++rr) {
        const int ii = it * 32 + ty + 8 * rr;
        const int k = kt * 32 + tx;
        R16[(size_t)ii * N_ + k] = f2b(tl[tx][ty + 8 * rr]);
      }
      __syncthreads();
    }
  }
}

// ---------------- G = eps @ L^T (one-time GEMM, lower-tri aware); zero bar ----------------
// r14: GR (row-major) only; GT deleted (loss phase now reads GR).
__global__ __launch_bounds__(256) void g_kernel(const float* __restrict__ eps,
                                                const uint16_t* __restrict__ Lr16,
                                                uint16_t* __restrict__ GR16,
                                                int* __restrict__ bar) {
  const int b = blockIdx.x;
  const int s0 = blockIdx.y * GS_;
  const int t = threadIdx.x;
  if (b == 0 && blockIdx.y == 0 && t < 64) bar[t] = 0;
  __shared__ __align__(16) uint16_t esh[GS_][N_];  // bf16 eps tile [s][n]
  const float* E = eps + ((size_t)b * S_ + s0) * N_;
  for (int p = 0; p < GS_; ++p) esh[p][t] = f2b(E[(size_t)p * N_ + t]);
  __syncthreads();

  const uint32_t* Lrow = (const uint32_t*)(Lr16 + (size_t)b * N_ * N_) + (size_t)t * (N_ / 2);
  float acc[GS_];
#pragma unroll
  for (int s = 0; s < GS_; ++s) acc[s] = 0.0f;
  const int jmax = (t >> 1) + 1;  // L[m][n] == 0 for n > m
  for (int j = 0; j < jmax; ++j) {
    const uint32_t lu = Lrow[j];
    const float l0 = blo(lu), l1 = bhi(lu);
#pragma unroll
    for (int s = 0; s < GS_; ++s) {
      const uint32_t eu = *(const uint32_t*)&esh[s][2 * j];
      acc[s] = fmaf(l1, bhi(eu), fmaf(l0, blo(eu), acc[s]));
    }
  }
  // GR[s][m]: coalesced across threads
  uint16_t* GRb = GR16 + ((size_t)b * S_ + s0) * N_ + t;
  for (int s = 0; s < GS_; ++s) GRb[(size_t)s * N_] = f2b(acc[s]);
}

// ---------------- solver: 4 blocks (1024 thr) per batch, grid 256, 1 block/CU ----------------
// r14 = r11 (proven best, 3530us) with ONE structural change: the loss phase reads GR
// (row-major) octet-cooperatively -- 8 lanes per scenario row, shfl-reduce, lane0 publishes.
// GT is DELETED: working set halves 128MB -> 64MB (fits L3), per-iter stream 77 -> 66MB.
// r11 counters said the solver is paced by beyond-L2 streaming (34MB/iter at 1.8TB/s ~= iter
// time); this targets exactly that. Also removes the B2 partial-reduce barrier + sc1 roundtrip.
// r13 lesson: hist stays in ORIGINAL layout (HIDX made clustered-key atomics same-bank, 4x
// conflicts); zeroing lives in the idle proj window.
__global__ __launch_bounds__(1024) void solve_kernel(
    const float* __restrict__ mu, const int* __restrict__ pcrisis,
    const int* __restrict__ plam, const uint16_t* __restrict__ GR16,
    unsigned* __restrict__ lossbits, int* __restrict__ bar, float* __restrict__ out) {
  const int bx = blockIdx.x;
  const int b = bx & (B_ - 1);
  const int part = bx >> 6;  // 0..3; blocks b+64k land on XCD b%8 under %8 RR
  const int t = threadIdx.x;
  const int ln = t & 63;
  const int s0 = part * SCH_;

  __shared__ __align__(16) float w_s[N_];
  __shared__ __align__(16) float scratch[8][N_];  // usum partials
  __shared__ __align__(16) uint16_t lists[S_];
  __shared__ __align__(16) int hist[4][256];
  __shared__ float c_sh;
  __shared__ int lcnt;
  __shared__ float sum_sh;

  const int crisis = pcrisis[0];
  const int lamv = plam[0];
  const float muf = 1.0f + ((lamv > 0) ? (1.0f / fmaxf((float)lamv, 0.1f)) : 0.0f);
  const float fl_bil = SAFETY_ * (float)crisis;
  const float mass = 1.0f - fl_bil;

  const float* muB = mu + (size_t)b * N_;
  const uint32_t* GRB = (const uint32_t*)(GR16 + (size_t)b * S_ * N_);

  const int wv = t >> 6;        // wave 0..15
  const int oc = (t >> 3) & 7;  // octet within wave
  const int u = t & 7;          // lane within octet

  // ---- w0 = proj(uniform) (wave 0) + initial hist/lcnt zero ----
  if (t < 64) {
    float y[4];
#pragma unroll
    for (int j = 0; j < 4; ++j) y[j] = 1.0f / (float)N_;
    proj_store(y, fl_bil, mass, muf, muB, ln, w_s, &c_sh);
  } else if (t < 576) {
    ((int*)hist)[t - 64] = 0;
    ((int*)hist)[t - 64 + 512] = 0;
    if (t == 64) lcnt = 0;
  }
  __syncthreads();  // B1

  for (int it = 0; it < NITER_; ++it) {
    const float cc = c_sh;
    unsigned* lgbuf = lossbits + ((it & 1) ? (size_t)B_ * S_ : 0) + (size_t)b * S_;

    // ---- loss from GR: 4 rounds x 128 rows; octet (8 lanes) owns one row per round.
    //      Coalesced 32B/octet (contiguous 4KB per wave); w broadcast from LDS (no conflict);
    //      3-step shfl reduce; lane0 publishes the key. No LDS partials, no extra barrier. ----
    {
      const float* wp = w_s + 2 * u;
#pragma unroll
      for (int k = 0; k < 4; ++k) {
        const int sl = k * 128 + wv * 8 + oc;
        if (sl < SCH_) {
          const uint32_t* row = GRB + (size_t)(s0 + sl) * (N_ / 2) + u;
          float acc = 0.0f;
#pragma unroll
          for (int m16 = 0; m16 < 16; ++m16) {
            const uint32_t g = row[8 * m16];
            const float2 wv2 = *(const float2*)&wp[16 * m16];
            acc = fmaf(blo(g), wv2.x, acc);
            acc = fmaf(bhi(g), wv2.y, acc);
          }
          acc += __shfl_xor(acc, 1);
          acc += __shfl_xor(acc, 2);
          acc += __shfl_xor(acc, 4);
          if (u == 0) {
            __hip_atomic_store(&lgbuf[s0 + sl], keyd(-(cc + acc)), __ATOMIC_RELAXED,
                               __HIP_MEMORY_SCOPE_AGENT);
          }
        }
      }
    }
    __syncthreads();  // B3 (drains vmcnt: key stores visible before arrival)

    // ---- per-batch spin barrier ----
    if (t == 0) {
      __hip_atomic_fetch_add(&bar[b], 1, __ATOMIC_RELAXED, __HIP_MEMORY_SCOPE_AGENT);
      const int target = PART_ * (it + 1);
      while (__hip_atomic_load(&bar[b], __ATOMIC_RELAXED, __HIP_MEMORY_SCOPE_AGENT) < target) {
        __builtin_amdgcn_s_sleep(1);
      }
    }
    __syncthreads();  // B4

    // ---- gather all 2000 keys (thread t owns scenarios 2t, 2t+1) + pass-0 hist ----
    uint32_t kx = 0xFFFFFFFFu, ky = 0xFFFFFFFFu;
    if (t < S_ / 2) {
      const unsigned long long two = __hip_atomic_load(
          (const unsigned long long*)(lgbuf + 2 * t), __ATOMIC_RELAXED, __HIP_MEMORY_SCOPE_AGENT);
      kx = (uint32_t)two;
      ky = (uint32_t)(two >> 32);
      atomicAdd(&hist[0][kx >> 24], 1);
      atomicAdd(&hist[0][ky >> 24], 1);
    }
    __syncthreads();  // B5

    // ---- 4-pass radix select: redundant all-wave scan ----
    unsigned pref = 0;
    int r = K_;
#pragma unroll
    for (int pass = 0; pass < 4; ++pass) {
      const int shift = 24 - 8 * pass;
      {
        const int4 c4 = *(const int4*)&hist[pass][4 * ln];
        const int c0 = c4.x, c1 = c4.y, c2 = c4.z, c3 = c4.w;
        const int tot = c0 + c1 + c2 + c3;
        int sc = tot;
#pragma unroll
        for (int off = 1; off < 64; off <<= 1) {
          const int o = __shfl_up(sc, off);
          if (ln >= off) sc += o;
        }
        const int excl = sc - tot;
        const bool has = (excl < r) && (r <= sc);
        const unsigned long long bal = __ballot(has);
        const int lstar = __ffsll(bal) - 1;
        const int bc0 = __shfl(c0, lstar);
        const int bc1 = __shfl(c1, lstar);
        const int bc2 = __shfl(c2, lstar);
        const int bexcl = __shfl(excl, lstar);
        const int rr = r - bexcl;
        int d, rn;
        if (rr <= bc0) { d = 0; rn = rr; }
        else if (rr <= bc0 + bc1) { d = 1; rn = rr - bc0; }
        else if (rr <= bc0 + bc1 + bc2) { d = 2; rn = rr - bc0 - bc1; }
        else { d = 3; rn = rr - bc0 - bc1 - bc2; }
        pref |= (unsigned)(4 * lstar + d) << shift;
        r = rn;
      }
      if (pass < 3) {
        const unsigned msk = 0xFFFFFFFFu << shift;
        const int nshift = shift - 8;
        if (t < S_ / 2) {
          if ((kx & msk) == pref) atomicAdd(&hist[pass + 1][(kx >> nshift) & 255], 1);
          if ((ky & msk) == pref) atomicAdd(&hist[pass + 1][(ky >> nshift) & 255], 1);
        }
      } else {
        if (t < S_ / 2) {
          if (kx <= pref) { const int p = atomicAdd(&lcnt, 1); lists[p] = (uint16_t)(2 * t); }
          if (ky <= pref) { const int p = atomicAdd(&lcnt, 1); lists[p] = (uint16_t)(2 * t + 1); }
        }
      }
      __syncthreads();  // B6..B9
    }

    const int cnt = lcnt;
    const float weight = 1.0f / (float)((cnt > K_) ? cnt : K_);

    // ---- usum partials: u = sum_sel G rows. 8 row-groups x 128 m-pairs ----
    {
      const int rt = t >> 7;
      const int np = t & 127;
      float a0 = 0.0f, a1 = 0.0f;
      for (int p = rt; p < cnt; p += 8) {
        const uint32_t uu = GRB[(size_t)lists[p] * (N_ / 2) + np];
        a0 += blo(uu);
        a1 += bhi(uu);
      }
      *(float2*)&scratch[rt][2 * np] = make_float2(a0, a1);
    }
    __syncthreads();  // B10

    // ---- w update + projection (wave 0); idle waves zero hist/lcnt for next iter ----
    if (t < 64) {
      float4 u4 = make_float4(0.0f, 0.0f, 0.0f, 0.0f);
#pragma unroll
      for (int oct = 0; oct < 8; ++oct) {
        const float4 x = *(const float4*)&scratch[oct][4 * ln];
        u4.x += x.x; u4.y += x.y; u4.z += x.z; u4.w += x.w;
      }
      const float lr = 0.5f / sqrtf((float)it + 1.0f);
      const float4 w4 = *(const float4*)(w_s + 4 * ln);
      const float4 m4 = *(const float4*)(muB + 4 * ln);
      float y[4];
      y[0] = w4.x + lr * (muf * m4.x + u4.x * weight);
      y[1] = w4.y + lr * (muf * m4.y + u4.y * weight);
      y[2] = w4.z + lr * (muf * m4.z + u4.z * weight);
      y[3] = w4.w + lr * (muf * m4.w + u4.w * weight);
      proj_store(y, fl_bil, mass, muf, muB, ln, w_s, &c_sh);
    } else if (t < 576) {
      ((int*)hist)[t - 64] = 0;
      ((int*)hist)[t - 64 + 512] = 0;
      if (t == 64) lcnt = 0;
    }
    __syncthreads();  // B11 (doubles as next iteration's B1)
  }

  // ---- output (part 0 only): w / (sum + 1e-8) ----
  if (part == 0) {
    if (t < 64) {
      const float4 w4 = *(const float4*)(w_s + 4 * ln);
      const float ssum = wred_f(w4.x + w4.y + w4.z + w4.w);
      if (ln == 0) sum_sh = ssum;
    }
    __syncthreads();
    if (t < N_) out[(size_t)b * N_ + t] = fmaxf(w_s[t], 0.0f) / (sum_sh + 1e-8f);
  }
}

extern "C" void kernel_launch(void* const* d_in, const int* in_sizes, int n_in,
                              void* d_out, int out_size, void* d_ws, size_t ws_size,
                              hipStream_t stream) {
  const float* mu = (const float*)d_in[0];
  const float* sigma = (const float*)d_in[1];
  const float* eps = (const float*)d_in[2];
  const int* crisis = (const int*)d_in[3];
  const int* lam = (const int*)d_in[4];
  float* out = (float*)d_out;
  float* ws = (float*)d_ws;

  uint16_t* Lr16 = (uint16_t*)(ws + OFF_LR16);
  uint16_t* GR16 = (uint16_t*)(ws + OFF_GR);
  float* Lc = ws + OFF_GR;  // fp32 L aliases GR slot (dead before g_kernel writes GR)
  unsigned* lossbits = (unsigned*)(ws + OFF_LOSS);
  int* bar = (int*)(ws + OFF_BAR);

  chol_kernel<<<dim3(B_), dim3(512), 0, stream>>>(sigma, Lc);
  lpack_kernel<<<dim3(B_), dim3(256), 0, stream>>>(Lc, Lr16);
  g_kernel<<<dim3(B_, S_ / GS_), dim3(256), 0, stream>>>(eps, Lr16, GR16, bar);

  solve_kernel<<<dim3(PART_ * B_), dim3(1024), 0, stream>>>(
      mu, crisis, lam, GR16, lossbits, bar, out);
}

// Round 8
// 4416.241 us; speedup vs baseline: 1.4083x; 1.4083x over previous
//
#include <hip/hip_runtime.h>
#include <stdint.h>

#define B_   64
#define N_   256
#define S_   2000
#define K_   100
#define BIL_ 4
#define NITER_ 200
#define JITTER_ 1e-4f
#define SAFETY_ 0.5f
#define PART_ 4
#define SCH_  (S_ / PART_)   // 500 scenarios per block
#define GS_   50             // scenarios per g_kernel block

// ---- ws layout (offsets in float units) ----
// r15: fp32 Lc occupies the dead LC16+LR16 slots exactly (B*N*N floats); lpack deleted.
#define OFF_LCF   ((size_t)0)                                   // fp32 L col-major [k][i]
#define OFF_GT    (OFF_LCF + (size_t)B_ * N_ * N_)              // bf16 G^T [b][m][s]
#define OFF_GR    (OFF_GT + (size_t)B_ * N_ * S_ / 2)           // bf16 G [b][s][m]
#define OFF_LOSS  (OFF_GR + (size_t)B_ * S_ * N_ / 2)           // uint loss keys, double-buffered
#define OFF_BAR   (OFF_LOSS + (size_t)2 * B_ * S_)              // int barrier counters

// ---------------- helpers ----------------
__device__ __forceinline__ float wred_f(float x) {
#pragma unroll
  for (int off = 32; off > 0; off >>= 1) x += __shfl_xor(x, off);
  return x;
}
__device__ __forceinline__ int wred_i(int x) {
#pragma unroll
  for (int off = 32; off > 0; off >>= 1) x += __shfl_xor(x, off);
  return x;
}
// monotone key: larger loss -> SMALLER key (top-K largest = K smallest keys)
__device__ __forceinline__ unsigned keyd(float x) {
  unsigned u = __float_as_uint(x);
  unsigned ku = (u & 0x80000000u) ? ~u : (u | 0x80000000u);
  return ~ku;
}
__device__ __forceinline__ uint16_t f2b(float f) {  // RNE fp32->bf16
  uint32_t u = __float_as_uint(f);
  uint32_t r = u + 0x7FFFu + ((u >> 16) & 1u);
  return (uint16_t)(r >> 16);
}
__device__ __forceinline__ float blo(uint32_t u) { return __uint_as_float(u << 16); }
__device__ __forceinline__ float bhi(uint32_t u) { return __uint_as_float(u & 0xFFFF0000u); }

// Michelot exact simplex projection (fixed point == reference sort formula); one wave.
__device__ __forceinline__ float michelot4(const float vp[4], float z) {
  bool act[4] = {true, true, true, true};
  float theta = 0.0f;
  int prev = -1;
  for (int pass = 0; pass < 300; ++pass) {
    float ls = 0.0f; int lc = 0;
#pragma unroll
    for (int j = 0; j < 4; ++j) { if (act[j]) { ls += vp[j]; lc += 1; } }
    ls = wred_f(ls);
    lc = wred_i(lc);
    theta = (ls - z) / (float)lc;
    if (lc == prev) break;
    prev = lc;
#pragma unroll
    for (int j = 0; j < 4; ++j) act[j] = (vp[j] > theta);
  }
  return theta;
}

__device__ __forceinline__ void proj_store(const float y[4], float fl_bil, float mass, float muf,
                                           const float* __restrict__ muB, int ln,
                                           float* w_s, float* c_sh) {
  float vp[4];
#pragma unroll
  for (int j = 0; j < 4; ++j) {
    const int n = 4 * ln + j;
    vp[j] = y[j] - ((n == BIL_) ? fl_bil : 0.0f);
  }
  const float theta = michelot4(vp, mass);
  const float4 m4 = *(const float4*)(muB + 4 * ln);
  const float mm[4] = {m4.x, m4.y, m4.z, m4.w};
  float wj[4];
  float cp = 0.0f;
#pragma unroll
  for (int j = 0; j < 4; ++j) {
    const int n = 4 * ln + j;
    wj[j] = fmaxf(vp[j] - theta, 0.0f) + ((n == BIL_) ? fl_bil : 0.0f);
    cp = fmaf(muf * mm[j], wj[j], cp);
  }
  cp = wred_f(cp);
  if (ln == 0) *c_sh = cp;
  *(float4*)(w_s + 4 * ln) = make_float4(wj[0], wj[1], wj[2], wj[3]);
}

// ---------------- Cholesky v3: one block (512 thr) per batch (proven r3) ----------------
__global__ __launch_bounds__(512) void chol_kernel(const float* __restrict__ sigma,
                                                   float* __restrict__ Lc) {
  const int b = blockIdx.x;
  const int tid = threadIdx.x;
  const int i = tid & 255;
  const int half = tid >> 8;
  const float* Sg = sigma + (size_t)b * N_ * N_;
  float* L = Lc + (size_t)b * N_ * N_;
  __shared__ __align__(16) float slab[248 * 8];
  __shared__ __align__(16) float spart[256][8];
  __shared__ __align__(16) float pnl[64];

  for (int j0 = 0; j0 < N_; j0 += 8) {
    for (int x = tid; x < j0 * 8; x += 512) {
      const int k = x >> 3, jj = x & 7;
      slab[x] = L[(size_t)k * N_ + (j0 + jj)];
    }
    float s[8];
    if (half == 0) {
#pragma unroll
      for (int jj = 0; jj < 8; ++jj) {
        float a = Sg[(size_t)(j0 + jj) * N_ + i];
        if (i == j0 + jj) a += JITTER_;
        s[jj] = a;
      }
    } else {
#pragma unroll
      for (int jj = 0; jj < 8; ++jj) s[jj] = 0.0f;
    }
    __syncthreads();

    const int kb = half ? (j0 >> 1) : 0;
    const int ke = half ? j0 : (j0 >> 1);
#pragma unroll 4
    for (int k = kb; k < ke; ++k) {
      const float lk = L[(size_t)k * N_ + i];
      const float4 h0 = *(const float4*)&slab[k * 8];
      const float4 h1 = *(const float4*)&slab[k * 8 + 4];
      s[0] = fmaf(-lk, h0.x, s[0]);
      s[1] = fmaf(-lk, h0.y, s[1]);
      s[2] = fmaf(-lk, h0.z, s[2]);
      s[3] = fmaf(-lk, h0.w, s[3]);
      s[4] = fmaf(-lk, h1.x, s[4]);
      s[5] = fmaf(-lk, h1.y, s[5]);
      s[6] = fmaf(-lk, h1.z, s[6]);
      s[7] = fmaf(-lk, h1.w, s[7]);
    }
    if (half == 1) {
      *(float4*)&spart[i][0] = make_float4(s[0], s[1], s[2], s[3]);
      *(float4*)&spart[i][4] = make_float4(s[4], s[5], s[6], s[7]);
    }
    __syncthreads();

    if (half == 0) {
      const float4 p0 = *(const float4*)&spart[i][0];
      const float4 p1 = *(const float4*)&spart[i][4];
      s[0] += p0.x; s[1] += p0.y; s[2] += p0.z; s[3] += p0.w;
      s[4] += p1.x; s[5] += p1.y; s[6] += p1.z; s[7] += p1.w;
      if ((i >> 3) == (j0 >> 3)) {
        const int base = j0 & 63;
        const int r = i & 7;
        float l[8], di[8];
#pragma unroll
        for (int m = 0; m < 8; ++m) {
          const float smv = __shfl(s[m], base + m);
          const float d = sqrtf(smv);
          const float dinv = 1.0f / d;
          di[m] = dinv;
          float lm;
          if (r == m) lm = d;
          else if (r > m) lm = s[m] * dinv;
          else lm = 0.0f;
          l[m] = lm;
#pragma unroll
          for (int mm = m + 1; mm < 8; ++mm) {
            s[mm] = fmaf(-lm, __shfl(lm, base + mm), s[mm]);
          }
        }
#pragma unroll
        for (int m = 0; m < 8; ++m) pnl[r * 8 + m] = (m < r) ? l[m] : ((m == r) ? di[r] : 0.0f);
#pragma unroll
        for (int m = 0; m < 8; ++m) L[(size_t)(j0 + m) * N_ + i] = l[m];
      }
    }
    __syncthreads();

    if (half == 0 && (i >> 3) != (j0 >> 3)) {
      float l[8];
      if (i > j0) {
#pragma unroll
        for (int m = 0; m < 8; ++m) {
          float sm = s[m];
#pragma unroll
          for (int mm = 0; mm < 8; ++mm) {
            if (mm < m) sm = fmaf(-l[mm], pnl[m * 8 + mm], sm);
          }
          l[m] = sm * pnl[m * 8 + m];
        }
      } else {
#pragma unroll
        for (int m = 0; m < 8; ++m) l[m] = 0.0f;
      }
#pragma unroll
      for (int m = 0; m < 8; ++m) L[(size_t)(j0 + m) * N_ + i] = l[m];
    }
    __syncthreads();
  }
}

// ---------------- G = eps @ L^T (one-time GEMM, lower-tri aware); zero bar ----------------
// r15: reads fp32 L (col-major Lc[n*N+m] = L[m][n]) and fp32 eps (LDS) -- lpack deleted,
// numerics strictly improve. G[s][m] = sum_n L[m][n]*eps[s][n]; thread t = asset m.
__global__ __launch_bounds__(256) void g_kernel(const float* __restrict__ eps,
                                                const float* __restrict__ Lc,
                                                uint16_t* __restrict__ GT16,
                                                uint16_t* __restrict__ GR16,
                                                int* __restrict__ bar) {
  const int b = blockIdx.x;
  const int s0 = blockIdx.y * GS_;
  const int t = threadIdx.x;
  if (b == 0 && blockIdx.y == 0 && t < 64) bar[t] = 0;
  __shared__ __align__(16) float esh[GS_][N_];  // fp32 eps tile [s][n] (51.2 KB)
  const float* E = eps + ((size_t)b * S_ + s0) * N_;
  for (int p = 0; p < GS_; ++p) esh[p][t] = E[(size_t)p * N_ + t];
  __syncthreads();

  const float* Lb = Lc + (size_t)b * N_ * N_;
  float acc[GS_];
#pragma unroll
  for (int s = 0; s < GS_; ++s) acc[s] = 0.0f;
  const int jmax = (t >> 1) + 1;  // covers n <= t (one extra zero element when t even)
  for (int j = 0; j < jmax; ++j) {
    const int n0 = 2 * j;
    const float l0 = Lb[(size_t)n0 * N_ + t];        // L[t][n0], coalesced across t
    const float l1 = Lb[(size_t)(n0 + 1) * N_ + t];  // L[t][n0+1] (0 above diagonal)
#pragma unroll
    for (int s = 0; s < GS_; ++s) {
      const float2 e = *(const float2*)&esh[s][n0];
      acc[s] = fmaf(l1, e.y, fmaf(l0, e.x, acc[s]));
    }
  }
  // GR[s][m]: coalesced across threads
  uint16_t* GRb = GR16 + ((size_t)b * S_ + s0) * N_ + t;
  for (int s = 0; s < GS_; ++s) GRb[(size_t)s * N_] = f2b(acc[s]);
  // GT[m][s]: 25 contiguous u32 per thread (s-pairs packed)
  uint32_t* GTb = (uint32_t*)(GT16 + (size_t)b * N_ * S_ + (size_t)t * S_ + s0);
#pragma unroll
  for (int u = 0; u < GS_ / 2; ++u) {
    const uint32_t pk = (uint32_t)f2b(acc[2 * u]) | ((uint32_t)f2b(acc[2 * u + 1]) << 16);
    GTb[u] = pk;
  }
}

// ---------------- solver: 4 blocks (1024 thr) per batch, grid 256, 1 block/CU ----------------
// r15 = r11 (proven 3530us) + own-key motion: publish phase stashes own keys in LDS (klocal)
// and pass-0-histograms them PRE-spin; gather reads only the 1500 foreign keys from global.
// hist/lcnt zeroing moved to the idle proj window (r13/r14-validated slot) so pre-spin
// atomics don't race the zeroing. Loss phase = r11's coalesced GT columns (r14 lesson:
// coalescing of the streaming phase dominates; r13 lesson: no hist bin remap).
__global__ __launch_bounds__(1024) void solve_kernel(
    const float* __restrict__ mu, const int* __restrict__ pcrisis,
    const int* __restrict__ plam, const uint16_t* __restrict__ GT16,
    const uint16_t* __restrict__ GR16, unsigned* __restrict__ lossbits,
    int* __restrict__ bar, float* __restrict__ out) {
  const int bx = blockIdx.x;
  const int b = bx & (B_ - 1);
  const int part = bx >> 6;  // 0..3; blocks b+64k land on XCD b%8 under %8 RR
  const int t = threadIdx.x;
  const int ln = t & 63;
  const int s0 = part * SCH_;

  __shared__ __align__(16) float w_s[N_];
  __shared__ __align__(16) float scratch[8][N_];  // loss partials (flat) / usum partials
  __shared__ __align__(16) uint16_t lists[S_];
  __shared__ __align__(16) int hist[4][256];
  __shared__ __align__(16) uint32_t klocal[SCH_];  // own keys (gather reads LDS not global)
  __shared__ float c_sh;
  __shared__ int lcnt;
  __shared__ float sum_sh;

  const int crisis = pcrisis[0];
  const int lamv = plam[0];
  const float muf = 1.0f + ((lamv > 0) ? (1.0f / fmaxf((float)lamv, 0.1f)) : 0.0f);
  const float fl_bil = SAFETY_ * (float)crisis;
  const float mass = 1.0f - fl_bil;

  const float* muB = mu + (size_t)b * N_;
  const uint32_t* GTB = (const uint32_t*)(GT16 + (size_t)b * N_ * S_);
  const uint32_t* GRB = (const uint32_t*)(GR16 + (size_t)b * S_ * N_);
  float* sc1 = &scratch[0][0];

  const int q = t >> 8;     // m-quarter (64 m)
  const int idx = t & 255;  // scenario-pair (idx < 250 active)
  const uint32_t* gcol = GTB + (size_t)(64 * q) * (S_ / 2) + (s0 >> 1) + idx;

  // ---- w0 = proj(uniform) (wave 0) + initial hist/lcnt zero ----
  if (t < 64) {
    float y[4];
#pragma unroll
    for (int j = 0; j < 4; ++j) y[j] = 1.0f / (float)N_;
    proj_store(y, fl_bil, mass, muf, muB, ln, w_s, &c_sh);
  } else if (t < 576) {
    ((int*)hist)[t - 64] = 0;
    ((int*)hist)[t - 64 + 512] = 0;
    if (t == 64) lcnt = 0;
  }
  __syncthreads();  // B1

  for (int it = 0; it < NITER_; ++it) {
    // ---- loss partials: a = G_s[64q..64q+63] . w, coalesced GT columns (r11) ----
    if (idx < SCH_ / 2) {
      float a0 = 0.0f, a1 = 0.0f;
#pragma unroll 8
      for (int j = 0; j < 64; ++j) {
        const uint32_t u = gcol[(size_t)j * (S_ / 2)];
        const float ww = w_s[64 * q + j];  // broadcast
        a0 = fmaf(blo(u), ww, a0);
        a1 = fmaf(bhi(u), ww, a1);
      }
      *(float2*)&sc1[q * SCH_ + 2 * idx] = make_float2(a0, a1);
    }
    __syncthreads();  // B2

    // ---- combine + publish keys + klocal stash + PRE-SPIN own pass-0 hist (t<500) ----
    unsigned* lgbuf = lossbits + ((it & 1) ? (size_t)B_ * S_ : 0) + (size_t)b * S_;
    if (t < SCH_) {
      const float lv = -(c_sh + ((sc1[t] + sc1[SCH_ + t]) + (sc1[2 * SCH_ + t] + sc1[3 * SCH_ + t])));
      const uint32_t k = keyd(lv);
      __hip_atomic_store(&lgbuf[s0 + t], k, __ATOMIC_RELAXED, __HIP_MEMORY_SCOPE_AGENT);
      klocal[t] = k;
      atomicAdd(&hist[0][k >> 24], 1);
    }
    __syncthreads();  // B3 (drains vmcnt: key stores visible before arrival)

    // ---- per-batch spin barrier ----
    if (t == 0) {
      __hip_atomic_fetch_add(&bar[b], 1, __ATOMIC_RELAXED, __HIP_MEMORY_SCOPE_AGENT);
      const int target = PART_ * (it + 1);
      while (__hip_atomic_load(&bar[b], __ATOMIC_RELAXED, __HIP_MEMORY_SCOPE_AGENT) < target) {
        __builtin_amdgcn_s_sleep(1);
      }
    }
    __syncthreads();  // B4

    // ---- gather: own keys from LDS, foreign 1500 from global (+ their pass-0 hist) ----
    uint32_t kx = 0xFFFFFFFFu, ky = 0xFFFFFFFFu;
    if (t < S_ / 2) {
      const int rel = t - (s0 >> 1);
      if ((unsigned)rel < (unsigned)(SCH_ / 2)) {
        kx = klocal[2 * rel];
        ky = klocal[2 * rel + 1];
      } else {
        const unsigned long long two = __hip_atomic_load(
            (const unsigned long long*)(lgbuf + 2 * t), __ATOMIC_RELAXED,
            __HIP_MEMORY_SCOPE_AGENT);
        kx = (uint32_t)two;
        ky = (uint32_t)(two >> 32);
        atomicAdd(&hist[0][kx >> 24], 1);
        atomicAdd(&hist[0][ky >> 24], 1);
      }
    }
    __syncthreads();  // B5

    // ---- 4-pass radix select: redundant all-wave scan ----
    unsigned pref = 0;
    int r = K_;
#pragma unroll
    for (int pass = 0; pass < 4; ++pass) {
      const int shift = 24 - 8 * pass;
      {
        const int4 c4 = *(const int4*)&hist[pass][4 * ln];
        const int c0 = c4.x, c1 = c4.y, c2 = c4.z, c3 = c4.w;
        const int tot = c0 + c1 + c2 + c3;
        int sc = tot;
#pragma unroll
        for (int off = 1; off < 64; off <<= 1) {
          const int o = __shfl_up(sc, off);
          if (ln >= off) sc += o;
        }
        const int excl = sc - tot;
        const bool has = (excl < r) && (r <= sc);
        const unsigned long long bal = __ballot(has);
        const int lstar = __ffsll(bal) - 1;
        const int bc0 = __shfl(c0, lstar);
        const int bc1 = __shfl(c1, lstar);
        const int bc2 = __shfl(c2, lstar);
        const int bexcl = __shfl(excl, lstar);
        const int rr = r - bexcl;
        int d, rn;
        if (rr <= bc0) { d = 0; rn = rr; }
        else if (rr <= bc0 + bc1) { d = 1; rn = rr - bc0; }
        else if (rr <= bc0 + bc1 + bc2) { d = 2; rn = rr - bc0 - bc1; }
        else { d = 3; rn = rr - bc0 - bc1 - bc2; }
        pref |= (unsigned)(4 * lstar + d) << shift;
        r = rn;
      }
      if (pass < 3) {
        const unsigned msk = 0xFFFFFFFFu << shift;
        const int nshift = shift - 8;
        if (t < S_ / 2) {
          if ((kx & msk) == pref) atomicAdd(&hist[pass + 1][(kx >> nshift) & 255], 1);
          if ((ky & msk) == pref) atomicAdd(&hist[pass + 1][(ky >> nshift) & 255], 1);
        }
      } else {
        if (t < S_ / 2) {
          if (kx <= pref) { const int p = atomicAdd(&lcnt, 1); lists[p] = (uint16_t)(2 * t); }
          if (ky <= pref) { const int p = atomicAdd(&lcnt, 1); lists[p] = (uint16_t)(2 * t + 1); }
        }
      }
      __syncthreads();  // B6..B9
    }

    const int cnt = lcnt;
    const float weight = 1.0f / (float)((cnt > K_) ? cnt : K_);

    // ---- usum partials: u = sum_sel G rows. 8 row-groups x 128 m-pairs ----
    {
      const int rt = t >> 7;
      const int np = t & 127;
      float a0 = 0.0f, a1 = 0.0f;
      for (int p = rt; p < cnt; p += 8) {
        const uint32_t u = GRB[(size_t)lists[p] * (N_ / 2) + np];
        a0 += blo(u);
        a1 += bhi(u);
      }
      *(float2*)&scratch[rt][2 * np] = make_float2(a0, a1);
    }
    __syncthreads();  // B10

    // ---- w update + projection (wave 0); idle waves zero hist/lcnt for next iter ----
    if (t < 64) {
      float4 u4 = make_float4(0.0f, 0.0f, 0.0f, 0.0f);
#pragma unroll
      for (int oct = 0; oct < 8; ++oct) {
        const float4 x = *(const float4*)&scratch[oct][4 * ln];
        u4.x += x.x; u4.y += x.y; u4.z += x.z; u4.w += x.w;
      }
      const float lr = 0.5f / sqrtf((float)it + 1.0f);
      const float4 w4 = *(const float4*)(w_s + 4 * ln);
      const float4 m4 = *(const float4*)(muB + 4 * ln);
      float y[4];
      y[0] = w4.x + lr * (muf * m4.x + u4.x * weight);
      y[1] = w4.y + lr * (muf * m4.y + u4.y * weight);
      y[2] = w4.z + lr * (muf * m4.z + u4.z * weight);
      y[3] = w4.w + lr * (muf * m4.w + u4.w * weight);
      proj_store(y, fl_bil, mass, muf, muB, ln, w_s, &c_sh);
    } else if (t < 576) {
      ((int*)hist)[t - 64] = 0;
      ((int*)hist)[t - 64 + 512] = 0;
      if (t == 64) lcnt = 0;
    }
    __syncthreads();  // B11 (doubles as next iteration's B1)
  }

  // ---- output (part 0 only): w / (sum + 1e-8) ----
  if (part == 0) {
    if (t < 64) {
      const float4 w4 = *(const float4*)(w_s + 4 * ln);
      const float ssum = wred_f(w4.x + w4.y + w4.z + w4.w);
      if (ln == 0) sum_sh = ssum;
    }
    __syncthreads();
    if (t < N_) out[(size_t)b * N_ + t] = fmaxf(w_s[t], 0.0f) / (sum_sh + 1e-8f);
  }
}

extern "C" void kernel_launch(void* const* d_in, const int* in_sizes, int n_in,
                              void* d_out, int out_size, void* d_ws, size_t ws_size,
                              hipStream_t stream) {
  const float* mu = (const float*)d_in[0];
  const float* sigma = (const float*)d_in[1];
  const float* eps = (const float*)d_in[2];
  const int* crisis = (const int*)d_in[3];
  const int* lam = (const int*)d_in[4];
  float* out = (float*)d_out;
  float* ws = (float*)d_ws;

  float* Lc = ws + OFF_LCF;
  uint16_t* GT16 = (uint16_t*)(ws + OFF_GT);
  uint16_t* GR16 = (uint16_t*)(ws + OFF_GR);
  unsigned* lossbits = (unsigned*)(ws + OFF_LOSS);
  int* bar = (int*)(ws + OFF_BAR);

  chol_kernel<<<dim3(B_), dim3(512), 0, stream>>>(sigma, Lc);
  g_kernel<<<dim3(B_, S_ / GS_), dim3(256), 0, stream>>>(eps, Lc, GT16, GR16, bar);

  solve_kernel<<<dim3(PART_ * B_), dim3(1024), 0, stream>>>(
      mu, crisis, lam, GT16, GR16, lossbits, bar, out);
}

// Round 9
// 3595.297 us; speedup vs baseline: 1.7299x; 1.2283x over previous
//
#include <hip/hip_runtime.h>
#include <stdint.h>

#define B_   64
#define N_   256
#define S_   2000
#define K_   100
#define BIL_ 4
#define NITER_ 200
#define JITTER_ 1e-4f
#define SAFETY_ 0.5f
#define PART_ 4
#define SCH_  (S_ / PART_)   // 500 scenarios per block
#define GS_   50             // scenarios per g_kernel block

// ---- ws layout (offsets in float units) ----
#define OFF_LCF   ((size_t)0)                                   // fp32 L col-major [n][m]
#define OFF_GT    (OFF_LCF + (size_t)B_ * N_ * N_)              // bf16 G^T [b][m][s]
#define OFF_GR    (OFF_GT + (size_t)B_ * N_ * S_ / 2)           // bf16 G [b][s][m]
#define OFF_LOSS  (OFF_GR + (size_t)B_ * S_ * N_ / 2)           // uint loss keys, double-buffered
#define OFF_BAR   (OFF_LOSS + (size_t)2 * B_ * S_)              // int barrier counters

// ---------------- helpers ----------------
__device__ __forceinline__ float wred_f(float x) {
#pragma unroll
  for (int off = 32; off > 0; off >>= 1) x += __shfl_xor(x, off);
  return x;
}
__device__ __forceinline__ int wred_i(int x) {
#pragma unroll
  for (int off = 32; off > 0; off >>= 1) x += __shfl_xor(x, off);
  return x;
}
// monotone key: larger loss -> SMALLER key (top-K largest = K smallest keys)
__device__ __forceinline__ unsigned keyd(float x) {
  unsigned u = __float_as_uint(x);
  unsigned ku = (u & 0x80000000u) ? ~u : (u | 0x80000000u);
  return ~ku;
}
__device__ __forceinline__ uint16_t f2b(float f) {  // RNE fp32->bf16
  uint32_t u = __float_as_uint(f);
  uint32_t r = u + 0x7FFFu + ((u >> 16) & 1u);
  return (uint16_t)(r >> 16);
}
__device__ __forceinline__ float blo(uint32_t u) { return __uint_as_float(u << 16); }
__device__ __forceinline__ float bhi(uint32_t u) { return __uint_as_float(u & 0xFFFF0000u); }

// Michelot exact simplex projection (fixed point == reference sort formula); one wave.
__device__ __forceinline__ float michelot4(const float vp[4], float z) {
  bool act[4] = {true, true, true, true};
  float theta = 0.0f;
  int prev = -1;
  for (int pass = 0; pass < 300; ++pass) {
    float ls = 0.0f; int lc = 0;
#pragma unroll
    for (int j = 0; j < 4; ++j) { if (act[j]) { ls += vp[j]; lc += 1; } }
    ls = wred_f(ls);
    lc = wred_i(lc);
    theta = (ls - z) / (float)lc;
    if (lc == prev) break;
    prev = lc;
#pragma unroll
    for (int j = 0; j < 4; ++j) act[j] = (vp[j] > theta);
  }
  return theta;
}

__device__ __forceinline__ void proj_store(const float y[4], float fl_bil, float mass, float muf,
                                           const float* __restrict__ muB, int ln,
                                           float* w_s, float* c_sh) {
  float vp[4];
#pragma unroll
  for (int j = 0; j < 4; ++j) {
    const int n = 4 * ln + j;
    vp[j] = y[j] - ((n == BIL_) ? fl_bil : 0.0f);
  }
  const float theta = michelot4(vp, mass);
  const float4 m4 = *(const float4*)(muB + 4 * ln);
  const float mm[4] = {m4.x, m4.y, m4.z, m4.w};
  float wj[4];
  float cp = 0.0f;
#pragma unroll
  for (int j = 0; j < 4; ++j) {
    const int n = 4 * ln + j;
    wj[j] = fmaxf(vp[j] - theta, 0.0f) + ((n == BIL_) ? fl_bil : 0.0f);
    cp = fmaf(muf * mm[j], wj[j], cp);
  }
  cp = wred_f(cp);
  if (ln == 0) *c_sh = cp;
  *(float4*)(w_s + 4 * ln) = make_float4(wj[0], wj[1], wj[2], wj[3]);
}

// ---------------- Cholesky v3: one block (512 thr) per batch (proven r3) ----------------
__global__ __launch_bounds__(512) void chol_kernel(const float* __restrict__ sigma,
                                                   float* __restrict__ Lc) {
  const int b = blockIdx.x;
  const int tid = threadIdx.x;
  const int i = tid & 255;
  const int half = tid >> 8;
  const float* Sg = sigma + (size_t)b * N_ * N_;
  float* L = Lc + (size_t)b * N_ * N_;
  __shared__ __align__(16) float slab[248 * 8];
  __shared__ __align__(16) float spart[256][8];
  __shared__ __align__(16) float pnl[64];

  for (int j0 = 0; j0 < N_; j0 += 8) {
    for (int x = tid; x < j0 * 8; x += 512) {
      const int k = x >> 3, jj = x & 7;
      slab[x] = L[(size_t)k * N_ + (j0 + jj)];
    }
    float s[8];
    if (half == 0) {
#pragma unroll
      for (int jj = 0; jj < 8; ++jj) {
        float a = Sg[(size_t)(j0 + jj) * N_ + i];
        if (i == j0 + jj) a += JITTER_;
        s[jj] = a;
      }
    } else {
#pragma unroll
      for (int jj = 0; jj < 8; ++jj) s[jj] = 0.0f;
    }
    __syncthreads();

    const int kb = half ? (j0 >> 1) : 0;
    const int ke = half ? j0 : (j0 >> 1);
#pragma unroll 4
    for (int k = kb; k < ke; ++k) {
      const float lk = L[(size_t)k * N_ + i];
      const float4 h0 = *(const float4*)&slab[k * 8];
      const float4 h1 = *(const float4*)&slab[k * 8 + 4];
      s[0] = fmaf(-lk, h0.x, s[0]);
      s[1] = fmaf(-lk, h0.y, s[1]);
      s[2] = fmaf(-lk, h0.z, s[2]);
      s[3] = fmaf(-lk, h0.w, s[3]);
      s[4] = fmaf(-lk, h1.x, s[4]);
      s[5] = fmaf(-lk, h1.y, s[5]);
      s[6] = fmaf(-lk, h1.z, s[6]);
      s[7] = fmaf(-lk, h1.w, s[7]);
    }
    if (half == 1) {
      *(float4*)&spart[i][0] = make_float4(s[0], s[1], s[2], s[3]);
      *(float4*)&spart[i][4] = make_float4(s[4], s[5], s[6], s[7]);
    }
    __syncthreads();

    if (half == 0) {
      const float4 p0 = *(const float4*)&spart[i][0];
      const float4 p1 = *(const float4*)&spart[i][4];
      s[0] += p0.x; s[1] += p0.y; s[2] += p0.z; s[3] += p0.w;
      s[4] += p1.x; s[5] += p1.y; s[6] += p1.z; s[7] += p1.w;
      if ((i >> 3) == (j0 >> 3)) {
        const int base = j0 & 63;
        const int r = i & 7;
        float l[8], di[8];
#pragma unroll
        for (int m = 0; m < 8; ++m) {
          const float smv = __shfl(s[m], base + m);
          const float d = sqrtf(smv);
          const float dinv = 1.0f / d;
          di[m] = dinv;
          float lm;
          if (r == m) lm = d;
          else if (r > m) lm = s[m] * dinv;
          else lm = 0.0f;
          l[m] = lm;
#pragma unroll
          for (int mm = m + 1; mm < 8; ++mm) {
            s[mm] = fmaf(-lm, __shfl(lm, base + mm), s[mm]);
          }
        }
#pragma unroll
        for (int m = 0; m < 8; ++m) pnl[r * 8 + m] = (m < r) ? l[m] : ((m == r) ? di[r] : 0.0f);
#pragma unroll
        for (int m = 0; m < 8; ++m) L[(size_t)(j0 + m) * N_ + i] = l[m];
      }
    }
    __syncthreads();

    if (half == 0 && (i >> 3) != (j0 >> 3)) {
      float l[8];
      if (i > j0) {
#pragma unroll
        for (int m = 0; m < 8; ++m) {
          float sm = s[m];
#pragma unroll
          for (int mm = 0; mm < 8; ++mm) {
            if (mm < m) sm = fmaf(-l[mm], pnl[m * 8 + mm], sm);
          }
          l[m] = sm * pnl[m * 8 + m];
        }
      } else {
#pragma unroll
        for (int m = 0; m < 8; ++m) l[m] = 0.0f;
      }
#pragma unroll
      for (int m = 0; m < 8; ++m) L[(size_t)(j0 + m) * N_ + i] = l[m];
    }
    __syncthreads();
  }
}

// ---------------- G = eps @ L^T (one-time GEMM, lower-tri aware); zero bar ----------------
// r16: L from fp32 Lc (coalesced columns, r15); eps staged PACKED bf16x2 in LDS (25.6 KB,
// restores 6-block/CU occupancy that r15's 51 KB fp32 tile halved).
__global__ __launch_bounds__(256) void g_kernel(const float* __restrict__ eps,
                                                const float* __restrict__ Lc,
                                                uint16_t* __restrict__ GT16,
                                                uint16_t* __restrict__ GR16,
                                                int* __restrict__ bar) {
  const int b = blockIdx.x;
  const int s0 = blockIdx.y * GS_;
  const int t = threadIdx.x;
  if (b == 0 && blockIdx.y == 0 && t < 64) bar[t] = 0;
  __shared__ __align__(16) uint32_t esh[GS_][N_ / 2];  // packed bf16 pair per u32
  const float* E = eps + ((size_t)b * S_ + s0) * N_;
  for (int x = t; x < GS_ * (N_ / 2); x += 256) {
    const int p = x >> 7, k = x & 127;
    const float2 e = *(const float2*)&E[(size_t)p * N_ + 2 * k];
    esh[p][k] = (uint32_t)f2b(e.x) | ((uint32_t)f2b(e.y) << 16);
  }
  __syncthreads();

  const float* Lb = Lc + (size_t)b * N_ * N_;
  float acc[GS_];
#pragma unroll
  for (int s = 0; s < GS_; ++s) acc[s] = 0.0f;
  const int jmax = (t >> 1) + 1;  // covers n <= t
  for (int j = 0; j < jmax; ++j) {
    const int n0 = 2 * j;
    const float l0 = Lb[(size_t)n0 * N_ + t];        // L[t][n0], coalesced across t
    const float l1 = Lb[(size_t)(n0 + 1) * N_ + t];  // L[t][n0+1] (0 above diagonal)
#pragma unroll
    for (int s = 0; s < GS_; ++s) {
      const uint32_t eu = esh[s][j];
      acc[s] = fmaf(l1, bhi(eu), fmaf(l0, blo(eu), acc[s]));
    }
  }
  // GR[s][m]: coalesced across threads
  uint16_t* GRb = GR16 + ((size_t)b * S_ + s0) * N_ + t;
  for (int s = 0; s < GS_; ++s) GRb[(size_t)s * N_] = f2b(acc[s]);
  // GT[m][s]: 25 contiguous u32 per thread (s-pairs packed)
  uint32_t* GTb = (uint32_t*)(GT16 + (size_t)b * N_ * S_ + (size_t)t * S_ + s0);
#pragma unroll
  for (int u = 0; u < GS_ / 2; ++u) {
    const uint32_t pk = (uint32_t)f2b(acc[2 * u]) | ((uint32_t)f2b(acc[2 * u + 1]) << 16);
    GTb[u] = pk;
  }
}

// ---------------- solver: 4 blocks (1024 thr) per batch, grid 256, 1 block/CU ----------------
// r16 = r15 + LDS-pinned half-slice: the block's GT slice (256 KB) is iteration-invariant;
// even-m rows (128 x 250 u32 = 125 KB) are staged into LDS ONCE, odd-m rows stream from
// L2/L3. Per-iter global GT traffic halves (64->32 MB chip-wide) and per-XCD L2 demand drops
// to ~capacity, attacking the measured 34 MB/iter L2-miss stream that paces the loss phase.
// unroll 4 keeps in-flight loads at r11's proven register footprint (spill tripwire: WRITE_SIZE).
__global__ __launch_bounds__(1024) void solve_kernel(
    const float* __restrict__ mu, const int* __restrict__ pcrisis,
    const int* __restrict__ plam, const uint16_t* __restrict__ GT16,
    const uint16_t* __restrict__ GR16, unsigned* __restrict__ lossbits,
    int* __restrict__ bar, float* __restrict__ out) {
  const int bx = blockIdx.x;
  const int b = bx & (B_ - 1);
  const int part = bx >> 6;  // 0..3; blocks b+64k land on XCD b%8 under %8 RR
  const int t = threadIdx.x;
  const int ln = t & 63;
  const int wv = t >> 6;
  const int s0 = part * SCH_;

  __shared__ __align__(16) uint32_t gts[128 * 250];  // even-m GT rows (125 KB, static)
  __shared__ __align__(16) float w_s[N_];
  __shared__ __align__(16) float scratch[8][N_];  // loss partials (flat) / usum partials
  __shared__ __align__(16) uint16_t lists[S_];
  __shared__ __align__(16) int hist[4][256];
  __shared__ __align__(16) uint32_t klocal[SCH_];  // own keys (gather reads LDS not global)
  __shared__ float c_sh;
  __shared__ int lcnt;
  __shared__ float sum_sh;

  const int crisis = pcrisis[0];
  const int lamv = plam[0];
  const float muf = 1.0f + ((lamv > 0) ? (1.0f / fmaxf((float)lamv, 0.1f)) : 0.0f);
  const float fl_bil = SAFETY_ * (float)crisis;
  const float mass = 1.0f - fl_bil;

  const float* muB = mu + (size_t)b * N_;
  const uint32_t* GTB = (const uint32_t*)(GT16 + (size_t)b * N_ * S_);
  const uint32_t* GRB = (const uint32_t*)(GR16 + (size_t)b * S_ * N_);
  float* sc1 = &scratch[0][0];

  const int q = t >> 8;     // m-quarter (64 m)
  const int idx = t & 255;  // scenario-pair (idx < 250 active)
  // odd-m column base for this thread's scenario-pair
  const uint32_t* gco = GTB + (size_t)(64 * q + 1) * (S_ / 2) + (s0 >> 1) + idx;

  // ---- one-time: stage even-m GT rows into LDS (row r holds m = 2r) ----
  for (int r = wv; r < 128; r += 16) {
    const uint32_t* src = GTB + (size_t)(2 * r) * (S_ / 2) + (s0 >> 1);
    for (int c = ln; c < 250; c += 64) gts[r * 250 + c] = src[c];
  }

  // ---- w0 = proj(uniform) (wave 0) + initial hist/lcnt zero ----
  if (t < 64) {
    float y[4];
#pragma unroll
    for (int j = 0; j < 4; ++j) y[j] = 1.0f / (float)N_;
    proj_store(y, fl_bil, mass, muf, muB, ln, w_s, &c_sh);
  } else if (t < 576) {
    ((int*)hist)[t - 64] = 0;
    ((int*)hist)[t - 64 + 512] = 0;
    if (t == 64) lcnt = 0;
  }
  __syncthreads();  // B1 (covers gts staging + w0)

  for (int it = 0; it < NITER_; ++it) {
    // ---- loss partials: even m from LDS, odd m from global (32 loads each) ----
    if (idx < SCH_ / 2) {
      float a0 = 0.0f, a1 = 0.0f;
      const uint32_t* lrow = &gts[(32 * q) * 250 + idx];
#pragma unroll 4
      for (int j = 0; j < 32; ++j) {
        const uint32_t ue = lrow[j * 250];               // m = 64q + 2j   (LDS)
        const uint32_t uo = gco[(size_t)j * S_];         // m = 64q + 2j+1 (global; stride 2*(S/2))
        const float we = w_s[64 * q + 2 * j];
        const float wo = w_s[64 * q + 2 * j + 1];
        a0 = fmaf(blo(ue), we, fmaf(blo(uo), wo, a0));
        a1 = fmaf(bhi(ue), we, fmaf(bhi(uo), wo, a1));
      }
      *(float2*)&sc1[q * SCH_ + 2 * idx] = make_float2(a0, a1);
    }
    __syncthreads();  // B2

    // ---- combine + publish keys + klocal stash + PRE-SPIN own pass-0 hist (t<500) ----
    unsigned* lgbuf = lossbits + ((it & 1) ? (size_t)B_ * S_ : 0) + (size_t)b * S_;
    if (t < SCH_) {
      const float lv = -(c_sh + ((sc1[t] + sc1[SCH_ + t]) + (sc1[2 * SCH_ + t] + sc1[3 * SCH_ + t])));
      const uint32_t k = keyd(lv);
      __hip_atomic_store(&lgbuf[s0 + t], k, __ATOMIC_RELAXED, __HIP_MEMORY_SCOPE_AGENT);
      klocal[t] = k;
      atomicAdd(&hist[0][k >> 24], 1);
    }
    __syncthreads();  // B3 (drains vmcnt: key stores visible before arrival)

    // ---- per-batch spin barrier ----
    if (t == 0) {
      __hip_atomic_fetch_add(&bar[b], 1, __ATOMIC_RELAXED, __HIP_MEMORY_SCOPE_AGENT);
      const int target = PART_ * (it + 1);
      while (__hip_atomic_load(&bar[b], __ATOMIC_RELAXED, __HIP_MEMORY_SCOPE_AGENT) < target) {
        __builtin_amdgcn_s_sleep(1);
      }
    }
    __syncthreads();  // B4

    // ---- gather: own keys from LDS, foreign 1500 from global (+ their pass-0 hist) ----
    uint32_t kx = 0xFFFFFFFFu, ky = 0xFFFFFFFFu;
    if (t < S_ / 2) {
      const int rel = t - (s0 >> 1);
      if ((unsigned)rel < (unsigned)(SCH_ / 2)) {
        kx = klocal[2 * rel];
        ky = klocal[2 * rel + 1];
      } else {
        const unsigned long long two = __hip_atomic_load(
            (const unsigned long long*)(lgbuf + 2 * t), __ATOMIC_RELAXED,
            __HIP_MEMORY_SCOPE_AGENT);
        kx = (uint32_t)two;
        ky = (uint32_t)(two >> 32);
        atomicAdd(&hist[0][kx >> 24], 1);
        atomicAdd(&hist[0][ky >> 24], 1);
      }
    }
    __syncthreads();  // B5

    // ---- 4-pass radix select: redundant all-wave scan ----
    unsigned pref = 0;
    int r = K_;
#pragma unroll
    for (int pass = 0; pass < 4; ++pass) {
      const int shift = 24 - 8 * pass;
      {
        const int4 c4 = *(const int4*)&hist[pass][4 * ln];
        const int c0 = c4.x, c1 = c4.y, c2 = c4.z, c3 = c4.w;
        const int tot = c0 + c1 + c2 + c3;
        int sc = tot;
#pragma unroll
        for (int off = 1; off < 64; off <<= 1) {
          const int o = __shfl_up(sc, off);
          if (ln >= off) sc += o;
        }
        const int excl = sc - tot;
        const bool has = (excl < r) && (r <= sc);
        const unsigned long long bal = __ballot(has);
        const int lstar = __ffsll(bal) - 1;
        const int bc0 = __shfl(c0, lstar);
        const int bc1 = __shfl(c1, lstar);
        const int bc2 = __shfl(c2, lstar);
        const int bexcl = __shfl(excl, lstar);
        const int rr = r - bexcl;
        int d, rn;
        if (rr <= bc0) { d = 0; rn = rr; }
        else if (rr <= bc0 + bc1) { d = 1; rn = rr - bc0; }
        else if (rr <= bc0 + bc1 + bc2) { d = 2; rn = rr - bc0 - bc1; }
        else { d = 3; rn = rr - bc0 - bc1 - bc2; }
        pref |= (unsigned)(4 * lstar + d) << shift;
        r = rn;
      }
      if (pass < 3) {
        const unsigned msk = 0xFFFFFFFFu << shift;
        const int nshift = shift - 8;
        if (t < S_ / 2) {
          if ((kx & msk) == pref) atomicAdd(&hist[pass + 1][(kx >> nshift) & 255], 1);
          if ((ky & msk) == pref) atomicAdd(&hist[pass + 1][(ky >> nshift) & 255], 1);
        }
      } else {
        if (t < S_ / 2) {
          if (kx <= pref) { const int p = atomicAdd(&lcnt, 1); lists[p] = (uint16_t)(2 * t); }
          if (ky <= pref) { const int p = atomicAdd(&lcnt, 1); lists[p] = (uint16_t)(2 * t + 1); }
        }
      }
      __syncthreads();  // B6..B9
    }

    const int cnt = lcnt;
    const float weight = 1.0f / (float)((cnt > K_) ? cnt : K_);

    // ---- usum partials: u = sum_sel G rows. 8 row-groups x 128 m-pairs ----
    {
      const int rt = t >> 7;
      const int np = t & 127;
      float a0 = 0.0f, a1 = 0.0f;
      for (int p = rt; p < cnt; p += 8) {
        const uint32_t u = GRB[(size_t)lists[p] * (N_ / 2) + np];
        a0 += blo(u);
        a1 += bhi(u);
      }
      *(float2*)&scratch[rt][2 * np] = make_float2(a0, a1);
    }
    __syncthreads();  // B10

    // ---- w update + projection (wave 0); idle waves zero hist/lcnt for next iter ----
    if (t < 64) {
      float4 u4 = make_float4(0.0f, 0.0f, 0.0f, 0.0f);
#pragma unroll
      for (int oct = 0; oct < 8; ++oct) {
        const float4 x = *(const float4*)&scratch[oct][4 * ln];
        u4.x += x.x; u4.y += x.y; u4.z += x.z; u4.w += x.w;
      }
      const float lr = 0.5f / sqrtf((float)it + 1.0f);
      const float4 w4 = *(const float4*)(w_s + 4 * ln);
      const float4 m4 = *(const float4*)(muB + 4 * ln);
      float y[4];
      y[0] = w4.x + lr * (muf * m4.x + u4.x * weight);
      y[1] = w4.y + lr * (muf * m4.y + u4.y * weight);
      y[2] = w4.z + lr * (muf * m4.z + u4.z * weight);
      y[3] = w4.w + lr * (muf * m4.w + u4.w * weight);
      proj_store(y, fl_bil, mass, muf, muB, ln, w_s, &c_sh);
    } else if (t < 576) {
      ((int*)hist)[t - 64] = 0;
      ((int*)hist)[t - 64 + 512] = 0;
      if (t == 64) lcnt = 0;
    }
    __syncthreads();  // B11 (doubles as next iteration's B1)
  }

  // ---- output (part 0 only): w / (sum + 1e-8) ----
  if (part == 0) {
    if (t < 64) {
      const float4 w4 = *(const float4*)(w_s + 4 * ln);
      const float ssum = wred_f(w4.x + w4.y + w4.z + w4.w);
      if (ln == 0) sum_sh = ssum;
    }
    __syncthreads();
    if (t < N_) out[(size_t)b * N_ + t] = fmaxf(w_s[t], 0.0f) / (sum_sh + 1e-8f);
  }
}

extern "C" void kernel_launch(void* const* d_in, const int* in_sizes, int n_in,
                              void* d_out, int out_size, void* d_ws, size_t ws_size,
                              hipStream_t stream) {
  const float* mu = (const float*)d_in[0];
  const float* sigma = (const float*)d_in[1];
  const float* eps = (const float*)d_in[2];
  const int* crisis = (const int*)d_in[3];
  const int* lam = (const int*)d_in[4];
  float* out = (float*)d_out;
  float* ws = (float*)d_ws;

  float* Lc = ws + OFF_LCF;
  uint16_t* GT16 = (uint16_t*)(ws + OFF_GT);
  uint16_t* GR16 = (uint16_t*)(ws + OFF_GR);
  unsigned* lossbits = (unsigned*)(ws + OFF_LOSS);
  int* bar = (int*)(ws + OFF_BAR);

  chol_kernel<<<dim3(B_), dim3(512), 0, stream>>>(sigma, Lc);
  g_kernel<<<dim3(B_, S_ / GS_), dim3(256), 0, stream>>>(eps, Lc, GT16, GR16, bar);

  solve_kernel<<<dim3(PART_ * B_), dim3(1024), 0, stream>>>(
      mu, crisis, lam, GT16, GR16, lossbits, bar, out);
}

// Round 10
// 3400.858 us; speedup vs baseline: 1.8288x; 1.0572x over previous
//
#include <hip/hip_runtime.h>
#include <stdint.h>

#define B_   64
#define N_   256
#define S_   2000
#define K_   100
#define BIL_ 4
#define NITER_ 200
#define JITTER_ 1e-4f
#define SAFETY_ 0.5f
#define PART_ 4
#define SCH_  (S_ / PART_)   // 500 scenarios per block
#define GS_   50             // scenarios per g_kernel block

// ---- ws layout (offsets in float units) ----
#define OFF_LCF   ((size_t)0)                                   // fp32 L col-major [n][m]
#define OFF_GT    (OFF_LCF + (size_t)B_ * N_ * N_)              // bf16 G^T [b][m][s]
#define OFF_GR    (OFF_GT + (size_t)B_ * N_ * S_ / 2)           // bf16 G [b][s][m]
#define OFF_LOSS  (OFF_GR + (size_t)B_ * S_ * N_ / 2)           // uint loss keys, double-buffered
#define OFF_BAR   (OFF_LOSS + (size_t)2 * B_ * S_)              // int barrier counters

// ---------------- helpers ----------------
__device__ __forceinline__ float wred_f(float x) {
#pragma unroll
  for (int off = 32; off > 0; off >>= 1) x += __shfl_xor(x, off);
  return x;
}
__device__ __forceinline__ int wred_i(int x) {
#pragma unroll
  for (int off = 32; off > 0; off >>= 1) x += __shfl_xor(x, off);
  return x;
}
// monotone key: larger loss -> SMALLER key (top-K largest = K smallest keys)
__device__ __forceinline__ unsigned keyd(float x) {
  unsigned u = __float_as_uint(x);
  unsigned ku = (u & 0x80000000u) ? ~u : (u | 0x80000000u);
  return ~ku;
}
__device__ __forceinline__ uint16_t f2b(float f) {  // RNE fp32->bf16
  uint32_t u = __float_as_uint(f);
  uint32_t r = u + 0x7FFFu + ((u >> 16) & 1u);
  return (uint16_t)(r >> 16);
}
__device__ __forceinline__ float blo(uint32_t u) { return __uint_as_float(u << 16); }
__device__ __forceinline__ float bhi(uint32_t u) { return __uint_as_float(u & 0xFFFF0000u); }

// Michelot exact simplex projection (fixed point == reference sort formula); one wave.
__device__ __forceinline__ float michelot4(const float vp[4], float z) {
  bool act[4] = {true, true, true, true};
  float theta = 0.0f;
  int prev = -1;
  for (int pass = 0; pass < 300; ++pass) {
    float ls = 0.0f; int lc = 0;
#pragma unroll
    for (int j = 0; j < 4; ++j) { if (act[j]) { ls += vp[j]; lc += 1; } }
    ls = wred_f(ls);
    lc = wred_i(lc);
    theta = (ls - z) / (float)lc;
    if (lc == prev) break;
    prev = lc;
#pragma unroll
    for (int j = 0; j < 4; ++j) act[j] = (vp[j] > theta);
  }
  return theta;
}

__device__ __forceinline__ void proj_store(const float y[4], float fl_bil, float mass, float muf,
                                           const float* __restrict__ muB, int ln,
                                           float* w_s, float* c_sh) {
  float vp[4];
#pragma unroll
  for (int j = 0; j < 4; ++j) {
    const int n = 4 * ln + j;
    vp[j] = y[j] - ((n == BIL_) ? fl_bil : 0.0f);
  }
  const float theta = michelot4(vp, mass);
  const float4 m4 = *(const float4*)(muB + 4 * ln);
  const float mm[4] = {m4.x, m4.y, m4.z, m4.w};
  float wj[4];
  float cp = 0.0f;
#pragma unroll
  for (int j = 0; j < 4; ++j) {
    const int n = 4 * ln + j;
    wj[j] = fmaxf(vp[j] - theta, 0.0f) + ((n == BIL_) ? fl_bil : 0.0f);
    cp = fmaf(muf * mm[j], wj[j], cp);
  }
  cp = wred_f(cp);
  if (ln == 0) *c_sh = cp;
  *(float4*)(w_s + 4 * ln) = make_float4(wj[0], wj[1], wj[2], wj[3]);
}

// ---------------- Cholesky v3: one block (512 thr) per batch (proven r3) ----------------
__global__ __launch_bounds__(512) void chol_kernel(const float* __restrict__ sigma,
                                                   float* __restrict__ Lc) {
  const int b = blockIdx.x;
  const int tid = threadIdx.x;
  const int i = tid & 255;
  const int half = tid >> 8;
  const float* Sg = sigma + (size_t)b * N_ * N_;
  float* L = Lc + (size_t)b * N_ * N_;
  __shared__ __align__(16) float slab[248 * 8];
  __shared__ __align__(16) float spart[256][8];
  __shared__ __align__(16) float pnl[64];

  for (int j0 = 0; j0 < N_; j0 += 8) {
    for (int x = tid; x < j0 * 8; x += 512) {
      const int k = x >> 3, jj = x & 7;
      slab[x] = L[(size_t)k * N_ + (j0 + jj)];
    }
    float s[8];
    if (half == 0) {
#pragma unroll
      for (int jj = 0; jj < 8; ++jj) {
        float a = Sg[(size_t)(j0 + jj) * N_ + i];
        if (i == j0 + jj) a += JITTER_;
        s[jj] = a;
      }
    } else {
#pragma unroll
      for (int jj = 0; jj < 8; ++jj) s[jj] = 0.0f;
    }
    __syncthreads();

    const int kb = half ? (j0 >> 1) : 0;
    const int ke = half ? j0 : (j0 >> 1);
#pragma unroll 4
    for (int k = kb; k < ke; ++k) {
      const float lk = L[(size_t)k * N_ + i];
      const float4 h0 = *(const float4*)&slab[k * 8];
      const float4 h1 = *(const float4*)&slab[k * 8 + 4];
      s[0] = fmaf(-lk, h0.x, s[0]);
      s[1] = fmaf(-lk, h0.y, s[1]);
      s[2] = fmaf(-lk, h0.z, s[2]);
      s[3] = fmaf(-lk, h0.w, s[3]);
      s[4] = fmaf(-lk, h1.x, s[4]);
      s[5] = fmaf(-lk, h1.y, s[5]);
      s[6] = fmaf(-lk, h1.z, s[6]);
      s[7] = fmaf(-lk, h1.w, s[7]);
    }
    if (half == 1) {
      *(float4*)&spart[i][0] = make_float4(s[0], s[1], s[2], s[3]);
      *(float4*)&spart[i][4] = make_float4(s[4], s[5], s[6], s[7]);
    }
    __syncthreads();

    if (half == 0) {
      const float4 p0 = *(const float4*)&spart[i][0];
      const float4 p1 = *(const float4*)&spart[i][4];
      s[0] += p0.x; s[1] += p0.y; s[2] += p0.z; s[3] += p0.w;
      s[4] += p1.x; s[5] += p1.y; s[6] += p1.z; s[7] += p1.w;
      if ((i >> 3) == (j0 >> 3)) {
        const int base = j0 & 63;
        const int r = i & 7;
        float l[8], di[8];
#pragma unroll
        for (int m = 0; m < 8; ++m) {
          const float smv = __shfl(s[m], base + m);
          const float d = sqrtf(smv);
          const float dinv = 1.0f / d;
          di[m] = dinv;
          float lm;
          if (r == m) lm = d;
          else if (r > m) lm = s[m] * dinv;
          else lm = 0.0f;
          l[m] = lm;
#pragma unroll
          for (int mm = m + 1; mm < 8; ++mm) {
            s[mm] = fmaf(-lm, __shfl(lm, base + mm), s[mm]);
          }
        }
#pragma unroll
        for (int m = 0; m < 8; ++m) pnl[r * 8 + m] = (m < r) ? l[m] : ((m == r) ? di[r] : 0.0f);
#pragma unroll
        for (int m = 0; m < 8; ++m) L[(size_t)(j0 + m) * N_ + i] = l[m];
      }
    }
    __syncthreads();

    if (half == 0 && (i >> 3) != (j0 >> 3)) {
      float l[8];
      if (i > j0) {
#pragma unroll
        for (int m = 0; m < 8; ++m) {
          float sm = s[m];
#pragma unroll
          for (int mm = 0; mm < 8; ++mm) {
            if (mm < m) sm = fmaf(-l[mm], pnl[m * 8 + mm], sm);
          }
          l[m] = sm * pnl[m * 8 + m];
        }
      } else {
#pragma unroll
        for (int m = 0; m < 8; ++m) l[m] = 0.0f;
      }
#pragma unroll
      for (int m = 0; m < 8; ++m) L[(size_t)(j0 + m) * N_ + i] = l[m];
    }
    __syncthreads();
  }
}

// ---------------- G = eps @ L^T (one-time GEMM, lower-tri aware); zero bar ----------------
// L from fp32 Lc (coalesced columns); eps staged packed bf16x2 in LDS (25.6 KB, 6 blocks/CU).
__global__ __launch_bounds__(256) void g_kernel(const float* __restrict__ eps,
                                                const float* __restrict__ Lc,
                                                uint16_t* __restrict__ GT16,
                                                uint16_t* __restrict__ GR16,
                                                int* __restrict__ bar) {
  const int b = blockIdx.x;
  const int s0 = blockIdx.y * GS_;
  const int t = threadIdx.x;
  if (b == 0 && blockIdx.y == 0 && t < 64) bar[t] = 0;
  __shared__ __align__(16) uint32_t esh[GS_][N_ / 2];  // packed bf16 pair per u32
  const float* E = eps + ((size_t)b * S_ + s0) * N_;
  for (int x = t; x < GS_ * (N_ / 2); x += 256) {
    const int p = x >> 7, k = x & 127;
    const float2 e = *(const float2*)&E[(size_t)p * N_ + 2 * k];
    esh[p][k] = (uint32_t)f2b(e.x) | ((uint32_t)f2b(e.y) << 16);
  }
  __syncthreads();

  const float* Lb = Lc + (size_t)b * N_ * N_;
  float acc[GS_];
#pragma unroll
  for (int s = 0; s < GS_; ++s) acc[s] = 0.0f;
  const int jmax = (t >> 1) + 1;  // covers n <= t
  for (int j = 0; j < jmax; ++j) {
    const int n0 = 2 * j;
    const float l0 = Lb[(size_t)n0 * N_ + t];        // L[t][n0], coalesced across t
    const float l1 = Lb[(size_t)(n0 + 1) * N_ + t];  // L[t][n0+1] (0 above diagonal)
#pragma unroll
    for (int s = 0; s < GS_; ++s) {
      const uint32_t eu = esh[s][j];
      acc[s] = fmaf(l1, bhi(eu), fmaf(l0, blo(eu), acc[s]));
    }
  }
  // GR[s][m]: coalesced across threads
  uint16_t* GRb = GR16 + ((size_t)b * S_ + s0) * N_ + t;
  for (int s = 0; s < GS_; ++s) GRb[(size_t)s * N_] = f2b(acc[s]);
  // GT[m][s]: 25 contiguous u32 per thread (s-pairs packed)
  uint32_t* GTb = (uint32_t*)(GT16 + (size_t)b * N_ * S_ + (size_t)t * S_ + s0);
#pragma unroll
  for (int u = 0; u < GS_ / 2; ++u) {
    const uint32_t pk = (uint32_t)f2b(acc[2 * u]) | ((uint32_t)f2b(acc[2 * u + 1]) << 16);
    GTb[u] = pk;
  }
}

// ---------------- solver: 4 blocks (1024 thr) per batch, grid 256, 1 block/CU ----------------
// r17 = r16 (proven 2900us: LDS-pinned even-m GT rows, pre-spin own hist, klocal gather)
// with the loss loop retuned for memory-level parallelism:
//  - w read as float4 (one read covers {we0,wo0,we1,wo1}): w ds_reads 64 -> 16 per thread/iter
//  - paired j-body, unroll 4 => 8 global (L2) loads in flight per thread (2x r16's MLP)
// Spill tripwire: WRITE_SIZE must stay 108064 (r10 lesson: 1024-thr kernels clamp at 64 VGPR).
__global__ __launch_bounds__(1024) void solve_kernel(
    const float* __restrict__ mu, const int* __restrict__ pcrisis,
    const int* __restrict__ plam, const uint16_t* __restrict__ GT16,
    const uint16_t* __restrict__ GR16, unsigned* __restrict__ lossbits,
    int* __restrict__ bar, float* __restrict__ out) {
  const int bx = blockIdx.x;
  const int b = bx & (B_ - 1);
  const int part = bx >> 6;  // 0..3; blocks b+64k land on XCD b%8 under %8 RR
  const int t = threadIdx.x;
  const int ln = t & 63;
  const int wv = t >> 6;
  const int s0 = part * SCH_;

  __shared__ __align__(16) uint32_t gts[128 * 250];  // even-m GT rows (125 KB, static)
  __shared__ __align__(16) float w_s[N_];
  __shared__ __align__(16) float scratch[8][N_];  // loss partials (flat) / usum partials
  __shared__ __align__(16) uint16_t lists[S_];
  __shared__ __align__(16) int hist[4][256];
  __shared__ __align__(16) uint32_t klocal[SCH_];  // own keys (gather reads LDS not global)
  __shared__ float c_sh;
  __shared__ int lcnt;
  __shared__ float sum_sh;

  const int crisis = pcrisis[0];
  const int lamv = plam[0];
  const float muf = 1.0f + ((lamv > 0) ? (1.0f / fmaxf((float)lamv, 0.1f)) : 0.0f);
  const float fl_bil = SAFETY_ * (float)crisis;
  const float mass = 1.0f - fl_bil;

  const float* muB = mu + (size_t)b * N_;
  const uint32_t* GTB = (const uint32_t*)(GT16 + (size_t)b * N_ * S_);
  const uint32_t* GRB = (const uint32_t*)(GR16 + (size_t)b * S_ * N_);
  float* sc1 = &scratch[0][0];

  const int q = t >> 8;     // m-quarter (64 m)
  const int idx = t & 255;  // scenario-pair (idx < 250 active)
  // odd-m column base for this thread's scenario-pair
  const uint32_t* gco = GTB + (size_t)(64 * q + 1) * (S_ / 2) + (s0 >> 1) + idx;

  // ---- one-time: stage even-m GT rows into LDS (row r holds m = 2r) ----
  for (int r = wv; r < 128; r += 16) {
    const uint32_t* src = GTB + (size_t)(2 * r) * (S_ / 2) + (s0 >> 1);
    for (int c = ln; c < 250; c += 64) gts[r * 250 + c] = src[c];
  }

  // ---- w0 = proj(uniform) (wave 0) + initial hist/lcnt zero ----
  if (t < 64) {
    float y[4];
#pragma unroll
    for (int j = 0; j < 4; ++j) y[j] = 1.0f / (float)N_;
    proj_store(y, fl_bil, mass, muf, muB, ln, w_s, &c_sh);
  } else if (t < 576) {
    ((int*)hist)[t - 64] = 0;
    ((int*)hist)[t - 64 + 512] = 0;
    if (t == 64) lcnt = 0;
  }
  __syncthreads();  // B1 (covers gts staging + w0)

  for (int it = 0; it < NITER_; ++it) {
    // ---- loss partials: even m from LDS, odd m from global; w via float4 ----
    if (idx < SCH_ / 2) {
      float a0 = 0.0f, a1 = 0.0f;
      const uint32_t* lrow = &gts[(32 * q) * 250 + idx];
#pragma unroll 4
      for (int j = 0; j < 32; j += 2) {
        const float4 w4 = *(const float4*)&w_s[64 * q + 2 * j];  // {we0,wo0,we1,wo1}
        const uint32_t ue0 = lrow[j * 250];                      // m = 64q+2j   (LDS)
        const uint32_t uo0 = gco[(size_t)j * S_];                // m = 64q+2j+1 (global)
        const uint32_t ue1 = lrow[(j + 1) * 250];                // m = 64q+2j+2 (LDS)
        const uint32_t uo1 = gco[(size_t)(j + 1) * S_];          // m = 64q+2j+3 (global)
        a0 = fmaf(blo(ue0), w4.x, fmaf(blo(uo0), w4.y, a0));
        a1 = fmaf(bhi(ue0), w4.x, fmaf(bhi(uo0), w4.y, a1));
        a0 = fmaf(blo(ue1), w4.z, fmaf(blo(uo1), w4.w, a0));
        a1 = fmaf(bhi(ue1), w4.z, fmaf(bhi(uo1), w4.w, a1));
      }
      *(float2*)&sc1[q * SCH_ + 2 * idx] = make_float2(a0, a1);
    }
    __syncthreads();  // B2

    // ---- combine + publish keys + klocal stash + PRE-SPIN own pass-0 hist (t<500) ----
    unsigned* lgbuf = lossbits + ((it & 1) ? (size_t)B_ * S_ : 0) + (size_t)b * S_;
    if (t < SCH_) {
      const float lv = -(c_sh + ((sc1[t] + sc1[SCH_ + t]) + (sc1[2 * SCH_ + t] + sc1[3 * SCH_ + t])));
      const uint32_t k = keyd(lv);
      __hip_atomic_store(&lgbuf[s0 + t], k, __ATOMIC_RELAXED, __HIP_MEMORY_SCOPE_AGENT);
      klocal[t] = k;
      atomicAdd(&hist[0][k >> 24], 1);
    }
    __syncthreads();  // B3 (drains vmcnt: key stores visible before arrival)

    // ---- per-batch spin barrier ----
    if (t == 0) {
      __hip_atomic_fetch_add(&bar[b], 1, __ATOMIC_RELAXED, __HIP_MEMORY_SCOPE_AGENT);
      const int target = PART_ * (it + 1);
      while (__hip_atomic_load(&bar[b], __ATOMIC_RELAXED, __HIP_MEMORY_SCOPE_AGENT) < target) {
        __builtin_amdgcn_s_sleep(1);
      }
    }
    __syncthreads();  // B4

    // ---- gather: own keys from LDS, foreign 1500 from global (+ their pass-0 hist) ----
    uint32_t kx = 0xFFFFFFFFu, ky = 0xFFFFFFFFu;
    if (t < S_ / 2) {
      const int rel = t - (s0 >> 1);
      if ((unsigned)rel < (unsigned)(SCH_ / 2)) {
        kx = klocal[2 * rel];
        ky = klocal[2 * rel + 1];
      } else {
        const unsigned long long two = __hip_atomic_load(
            (const unsigned long long*)(lgbuf + 2 * t), __ATOMIC_RELAXED,
            __HIP_MEMORY_SCOPE_AGENT);
        kx = (uint32_t)two;
        ky = (uint32_t)(two >> 32);
        atomicAdd(&hist[0][kx >> 24], 1);
        atomicAdd(&hist[0][ky >> 24], 1);
      }
    }
    __syncthreads();  // B5

    // ---- 4-pass radix select: redundant all-wave scan ----
    unsigned pref = 0;
    int r = K_;
#pragma unroll
    for (int pass = 0; pass < 4; ++pass) {
      const int shift = 24 - 8 * pass;
      {
        const int4 c4 = *(const int4*)&hist[pass][4 * ln];
        const int c0 = c4.x, c1 = c4.y, c2 = c4.z, c3 = c4.w;
        const int tot = c0 + c1 + c2 + c3;
        int sc = tot;
#pragma unroll
        for (int off = 1; off < 64; off <<= 1) {
          const int o = __shfl_up(sc, off);
          if (ln >= off) sc += o;
        }
        const int excl = sc - tot;
        const bool has = (excl < r) && (r <= sc);
        const unsigned long long bal = __ballot(has);
        const int lstar = __ffsll(bal) - 1;
        const int bc0 = __shfl(c0, lstar);
        const int bc1 = __shfl(c1, lstar);
        const int bc2 = __shfl(c2, lstar);
        const int bexcl = __shfl(excl, lstar);
        const int rr = r - bexcl;
        int d, rn;
        if (rr <= bc0) { d = 0; rn = rr; }
        else if (rr <= bc0 + bc1) { d = 1; rn = rr - bc0; }
        else if (rr <= bc0 + bc1 + bc2) { d = 2; rn = rr - bc0 - bc1; }
        else { d = 3; rn = rr - bc0 - bc1 - bc2; }
        pref |= (unsigned)(4 * lstar + d) << shift;
        r = rn;
      }
      if (pass < 3) {
        const unsigned msk = 0xFFFFFFFFu << shift;
        const int nshift = shift - 8;
        if (t < S_ / 2) {
          if ((kx & msk) == pref) atomicAdd(&hist[pass + 1][(kx >> nshift) & 255], 1);
          if ((ky & msk) == pref) atomicAdd(&hist[pass + 1][(ky >> nshift) & 255], 1);
        }
      } else {
        if (t < S_ / 2) {
          if (kx <= pref) { const int p = atomicAdd(&lcnt, 1); lists[p] = (uint16_t)(2 * t); }
          if (ky <= pref) { const int p = atomicAdd(&lcnt, 1); lists[p] = (uint16_t)(2 * t + 1); }
        }
      }
      __syncthreads();  // B6..B9
    }

    const int cnt = lcnt;
    const float weight = 1.0f / (float)((cnt > K_) ? cnt : K_);

    // ---- usum partials: u = sum_sel G rows. 8 row-groups x 128 m-pairs ----
    {
      const int rt = t >> 7;
      const int np = t & 127;
      float a0 = 0.0f, a1 = 0.0f;
      for (int p = rt; p < cnt; p += 8) {
        const uint32_t u = GRB[(size_t)lists[p] * (N_ / 2) + np];
        a0 += blo(u);
        a1 += bhi(u);
      }
      *(float2*)&scratch[rt][2 * np] = make_float2(a0, a1);
    }
    __syncthreads();  // B10

    // ---- w update + projection (wave 0); idle waves zero hist/lcnt for next iter ----
    if (t < 64) {
      float4 u4 = make_float4(0.0f, 0.0f, 0.0f, 0.0f);
#pragma unroll
      for (int oct = 0; oct < 8; ++oct) {
        const float4 x = *(const float4*)&scratch[oct][4 * ln];
        u4.x += x.x; u4.y += x.y; u4.z += x.z; u4.w += x.w;
      }
      const float lr = 0.5f / sqrtf((float)it + 1.0f);
      const float4 w4 = *(const float4*)(w_s + 4 * ln);
      const float4 m4 = *(const float4*)(muB + 4 * ln);
      float y[4];
      y[0] = w4.x + lr * (muf * m4.x + u4.x * weight);
      y[1] = w4.y + lr * (muf * m4.y + u4.y * weight);
      y[2] = w4.z + lr * (muf * m4.z + u4.z * weight);
      y[3] = w4.w + lr * (muf * m4.w + u4.w * weight);
      proj_store(y, fl_bil, mass, muf, muB, ln, w_s, &c_sh);
    } else if (t < 576) {
      ((int*)hist)[t - 64] = 0;
      ((int*)hist)[t - 64 + 512] = 0;
      if (t == 64) lcnt = 0;
    }
    __syncthreads();  // B11 (doubles as next iteration's B1)
  }

  // ---- output (part 0 only): w / (sum + 1e-8) ----
  if (part == 0) {
    if (t < 64) {
      const float4 w4 = *(const float4*)(w_s + 4 * ln);
      const float ssum = wred_f(w4.x + w4.y + w4.z + w4.w);
      if (ln == 0) sum_sh = ssum;
    }
    __syncthreads();
    if (t < N_) out[(size_t)b * N_ + t] = fmaxf(w_s[t], 0.0f) / (sum_sh + 1e-8f);
  }
}

extern "C" void kernel_launch(void* const* d_in, const int* in_sizes, int n_in,
                              void* d_out, int out_size, void* d_ws, size_t ws_size,
                              hipStream_t stream) {
  const float* mu = (const float*)d_in[0];
  const float* sigma = (const float*)d_in[1];
  const float* eps = (const float*)d_in[2];
  const int* crisis = (const int*)d_in[3];
  const int* lam = (const int*)d_in[4];
  float* out = (float*)d_out;
  float* ws = (float*)d_ws;

  float* Lc = ws + OFF_LCF;
  uint16_t* GT16 = (uint16_t*)(ws + OFF_GT);
  uint16_t* GR16 = (uint16_t*)(ws + OFF_GR);
  unsigned* lossbits = (unsigned*)(ws + OFF_LOSS);
  int* bar = (int*)(ws + OFF_BAR);

  chol_kernel<<<dim3(B_), dim3(512), 0, stream>>>(sigma, Lc);
  g_kernel<<<dim3(B_, S_ / GS_), dim3(256), 0, stream>>>(eps, Lc, GT16, GR16, bar);

  solve_kernel<<<dim3(PART_ * B_), dim3(1024), 0, stream>>>(
      mu, crisis, lam, GT16, GR16, lossbits, bar, out);
}